// Round 4
// baseline (694.249 us; speedup 1.0000x reference)
//
#include <hip/hip_runtime.h>
#include <hip/hip_bf16.h>
#include <math.h>

#define S 4096
#define CIN 256
#define C3 768
#define NH 8
#define HD 32
#define KSPLIT 4

static constexpr float EPS = 1e-4f;

typedef __attribute__((ext_vector_type(8))) __bf16 bf16x8;
typedef __attribute__((ext_vector_type(4))) float f32x4;
typedef __attribute__((ext_vector_type(16))) float f32x16;
typedef __attribute__((ext_vector_type(8))) unsigned short u16x8;
typedef __attribute__((ext_vector_type(4))) unsigned u32x4;

static inline __device__ ushort f2bf(float f) {  // RN-even
  unsigned u = __float_as_uint(f);
  return (ushort)((u + 0x7fffu + ((u >> 16) & 1u)) >> 16);
}

// v_cvt_pk_bf16_f32: dst.lo16 = bf16(lo), dst.hi16 = bf16(hi); RNE (no builtin)
static inline __device__ unsigned cvt_pk_bf16(float lo, float hi) {
  unsigned r;
  asm("v_cvt_pk_bf16_f32 %0, %1, %2" : "=v"(r) : "v"(lo), "v"(hi));
  return r;
}
// v_permlane32_swap_b32: a.hi32lanes <-> b.lo32lanes.
static inline __device__ void plane32_swap(unsigned& a, unsigned& b) {
  asm("v_permlane32_swap_b32 %0, %1" : "+v"(a), "+v"(b));
}

#define EXP2 __builtin_amdgcn_exp2f

// Convert one 32x32 QK score tile (D-layout: col=q=lane&31, row=k=(r&3)+8*(r>>2)+4*hi)
// to two PV operand fragments (col/row=q, k = frag*8 elements at 8*hi+j) fully
// in registers: 8 cvt_pk + 4 permlane32_swap. plo covers k 0..15, phi 16..31.
static inline __device__ void s_to_pf(const f32x16 s, bf16x8& plo, bf16x8& phi) {
  unsigned c0 = cvt_pk_bf16(EXP2(s[0]), EXP2(s[1]));    // hi0:k(0,1)   hi1:k(4,5)
  unsigned c1 = cvt_pk_bf16(EXP2(s[2]), EXP2(s[3]));    // hi0:k(2,3)   hi1:k(6,7)
  unsigned c2 = cvt_pk_bf16(EXP2(s[4]), EXP2(s[5]));    // hi0:k(8,9)   hi1:k(12,13)
  unsigned c3 = cvt_pk_bf16(EXP2(s[6]), EXP2(s[7]));    // hi0:k(10,11) hi1:k(14,15)
  plane32_swap(c0, c2);
  plane32_swap(c1, c3);
  u32x4 lo4 = {c0, c1, c2, c3};
  plo = __builtin_bit_cast(bf16x8, lo4);
  unsigned c4 = cvt_pk_bf16(EXP2(s[8]), EXP2(s[9]));
  unsigned c5 = cvt_pk_bf16(EXP2(s[10]), EXP2(s[11]));
  unsigned c6 = cvt_pk_bf16(EXP2(s[12]), EXP2(s[13]));
  unsigned c7 = cvt_pk_bf16(EXP2(s[14]), EXP2(s[15]));
  plane32_swap(c4, c6);
  plane32_swap(c5, c7);
  u32x4 hi4 = {c4, c5, c6, c7};
  phi = __builtin_bit_cast(bf16x8, hi4);
}

// ---------------- weight norm (both weights, one launch) ---------------------
__global__ __launch_bounds__(256) void wnorm_kernel(const float* __restrict__ w_qkv,
                                                    const float* __restrict__ w_out,
                                                    ushort* __restrict__ wqb,
                                                    ushort* __restrict__ wob) {
  const int row = blockIdx.x * 4 + (threadIdx.x >> 6);
  const int lane = threadIdx.x & 63;
  const bool is_q = row < C3;
  const float* wr = (is_q ? w_qkv + (size_t)row * CIN : w_out + (size_t)(row - C3) * CIN);
  float v0 = wr[lane], v1 = wr[lane + 64], v2 = wr[lane + 128], v3 = wr[lane + 192];
  float ss = v0 * v0 + v1 * v1 + v2 * v2 + v3 * v3;
  #pragma unroll
  for (int off = 32; off > 0; off >>= 1) ss += __shfl_down(ss, off, 64);
  ss = __shfl(ss, 0, 64);
  const float scale = 1.0f / (sqrtf(ss) + 16.0f * EPS);
  ushort* whr = (is_q ? wqb + (size_t)row * CIN : wob + (size_t)(row - C3) * CIN);
  whr[lane] = f2bf(v0 * scale);
  whr[lane + 64] = f2bf(v1 * scale);
  whr[lane + 128] = f2bf(v2 * scale);
  whr[lane + 192] = f2bf(v3 * scale);
}

// ---------------- X [b][c][s] fp32 -> Xt [b][s][c] bf16 ----------------------
__global__ __launch_bounds__(256) void xt_kernel(const float* __restrict__ X,
                                                 ushort* __restrict__ Xt) {
  const int b = blockIdx.z;
  const int s0 = blockIdx.x * 64, c0 = blockIdx.y * 64;
  __shared__ ushort T[64][72];
  const int tc = threadIdx.x >> 4;
  const int ts = threadIdx.x & 15;
  #pragma unroll
  for (int i = 0; i < 4; i++) {
    const float4 v = *(const float4*)&X[((size_t)(b * CIN + c0 + tc + 16 * i)) * S + s0 + ts * 4];
    ushort4 u;
    u.x = f2bf(v.x); u.y = f2bf(v.y); u.z = f2bf(v.z); u.w = f2bf(v.w);
    *(ushort4*)&T[tc + 16 * i][ts * 4] = u;
  }
  __syncthreads();
  #pragma unroll
  for (int i = 0; i < 4; i++) {
    const int sr = tc + 16 * i;
    ushort4 u;
    u.x = T[ts * 4 + 0][sr];
    u.y = T[ts * 4 + 1][sr];
    u.z = T[ts * 4 + 2][sr];
    u.w = T[ts * 4 + 3][sr];
    *(ushort4*)&Xt[((size_t)b * S + s0 + sr) * CIN + c0 + ts * 4] = u;
  }
}

// ---------------- conv1 fused with pixel-norm + layout fan-out ---------------
// Q written as [bh][q][HD] rows (loaded once per attn wave). K and V written in
// MFMA-FRAGMENT-ORDERED PANELS so every attn fragment load is base + lane*16B
// (dense 1KB/instruction, 8 cache lines instead of 32-64):
//   Kpan: [bh][key>>5][half][key&31][hi][8]  (half = ch/16, hi = (ch&15)>>3)
//   Vpan: [bh][key>>6][kc][d][hi][8]         (kc = (key&63)>>4, hi = (key&15)>>3)
__global__ __launch_bounds__(256) void conv1_fused_kernel(const ushort* __restrict__ W,
                                                          const ushort* __restrict__ Bm,
                                                          ushort* __restrict__ Qn,
                                                          ushort* __restrict__ Kn,
                                                          ushort* __restrict__ Vt) {
  const int b = blockIdx.z;
  const int wid = threadIdx.x >> 6, lane = threadIdx.x & 63;
  const int col = lane & 15, quad = lane >> 4;
  const int m0 = blockIdx.y * 64 + (wid >> 1) * 32;  // 32-aligned: one head group
  const int n0 = blockIdx.x * 128 + (wid & 1) * 64;
  const ushort* Bb = Bm + (size_t)b * S * CIN;
  f32x4 acc[2][4] = {};
  #pragma unroll
  for (int k0 = 0; k0 < CIN; k0 += 32) {
    bf16x8 af[2], bf[4];
    #pragma unroll
    for (int mi = 0; mi < 2; mi++)
      af[mi] = *(const bf16x8*)&W[(size_t)(m0 + mi * 16 + col) * CIN + k0 + quad * 8];
    #pragma unroll
    for (int ni = 0; ni < 4; ni++)
      bf[ni] = *(const bf16x8*)&Bb[(size_t)(n0 + ni * 16 + col) * CIN + k0 + quad * 8];
    #pragma unroll
    for (int mi = 0; mi < 2; mi++)
      #pragma unroll
      for (int ni = 0; ni < 4; ni++)
        acc[mi][ni] = __builtin_amdgcn_mfma_f32_16x16x32_bf16(af[mi], bf[ni], acc[mi][ni], 0, 0, 0);
  }

  const int g = m0 >> 5;   // 0..23: group; 0-7 Q, 8-15 K, 16-23 V
  const int h = g & 7;
  float rn[4];
  #pragma unroll
  for (int ni = 0; ni < 4; ni++) {
    float ss = 0.f;
    #pragma unroll
    for (int mi = 0; mi < 2; mi++)
      #pragma unroll
      for (int r = 0; r < 4; r++) ss += acc[mi][ni][r] * acc[mi][ni][r];
    ss += __shfl_xor(ss, 16, 64);
    ss += __shfl_xor(ss, 32, 64);
    rn[ni] = rsqrtf(ss * (1.0f / HD) + EPS);
    if (g < 8) rn[ni] *= 0.2550348190698169f;  // log2(e)/sqrt(32) folded into Q
  }

  if (g < 8) {  // Q: row layout [q][HD]
    ushort* dst = Qn + (size_t)(b * NH + h) * S * HD;
    #pragma unroll
    for (int mi = 0; mi < 2; mi++)
      #pragma unroll
      for (int ni = 0; ni < 4; ni++) {
        ushort4 u;
        u.x = f2bf(acc[mi][ni][0] * rn[ni]);
        u.y = f2bf(acc[mi][ni][1] * rn[ni]);
        u.z = f2bf(acc[mi][ni][2] * rn[ni]);
        u.w = f2bf(acc[mi][ni][3] * rn[ni]);
        *(ushort4*)&dst[(size_t)(n0 + ni * 16 + col) * HD + mi * 16 + quad * 4] = u;
      }
  } else if (g < 16) {  // K: fragment panels
    // key = n0 + ni*16 + col; ch = mi*16 + quad*4 + r
    ushort* dst = Kn + (size_t)(b * NH + h) * S * HD + (size_t)(n0 >> 5) * 1024;
    #pragma unroll
    for (int mi = 0; mi < 2; mi++)
      #pragma unroll
      for (int ni = 0; ni < 4; ni++) {
        ushort4 u;
        u.x = f2bf(acc[mi][ni][0] * rn[ni]);
        u.y = f2bf(acc[mi][ni][1] * rn[ni]);
        u.z = f2bf(acc[mi][ni][2] * rn[ni]);
        u.w = f2bf(acc[mi][ni][3] * rn[ni]);
        *(ushort4*)&dst[(ni >> 1) * 1024 + mi * 512 + ((ni & 1) * 16 + col) * 16 +
                        (quad >> 1) * 8 + (quad & 1) * 4] = u;
      }
  } else {  // V: fragment panels (d = mi*16+quad*4+r, key = n0+ni*16+col)
    ushort* dst = Vt + (size_t)(b * NH + h) * HD * S + (size_t)(n0 >> 6) * 2048;
    #pragma unroll
    for (int mi = 0; mi < 2; mi++)
      #pragma unroll
      for (int ni = 0; ni < 4; ni++)
        #pragma unroll
        for (int r = 0; r < 4; r++)
          dst[ni * 512 + (mi * 16 + quad * 4 + r) * 16 + col] =
              f2bf(acc[mi][ni][r] * rn[ni]);
  }
}

// ---------------- MFMA attention: 32x32 tiles, P in registers ----------------
// S^T = K.Q^T via mfma_32x32x16 (Q pre-scaled -> exp2 direct). P rebuilt into
// the PV operand fragment in registers (T12). K/V read from fragment-ordered
// panels: every load is base + lane*16B (dense 1KB). K AND V prefetched one
// 64-key tile ahead. l via ones-MFMA (on the MFMA pipe). Zero LDS.
// KSPLIT=4: 2048 blocks = 8 blocks/CU = 32 waves/CU (kernel is 52 VGPR, fits
// the 64-VGPR/8-wave cap WITHOUT spilling -- R2's spill was the e[16] variant).
// Bijective XCD swizzle: each XCD owns 8 complete (b,kp,h) groups -> K/V
// working set ~1MB, L2-resident. grid 2048 x 256 (4 waves).
__global__ __launch_bounds__(256, 8) void attn_kernel(const ushort* __restrict__ Qn,
                                                      const ushort* __restrict__ Kn,
                                                      const ushort* __restrict__ Vt,
                                                      float* __restrict__ accP,
                                                      float* __restrict__ lP) {
  const int NWG = (S / 128) * NH * KSPLIT * 2;
  const int bid = blockIdx.x;
  const int id = (bid & 7) * (NWG / 8) + (bid >> 3);  // XCD = bid&7 gets NWG/8 consecutive ids
  const int qt = id & 31;
  const int grp = id >> 5;      // ((b*KSPLIT + kp) << 3) | h
  const int h = grp & 7;
  const int kp = (grp >> 3) & (KSPLIT - 1);
  const int b = (grp >> 3) / KSPLIT;
  const int wid = threadIdx.x >> 6, lane = threadIdx.x & 63;
  const int ln = lane & 31, hi = lane >> 5;
  const int q0 = qt * 128 + wid * 32;

  const ushort* Qh = Qn + (size_t)(b * NH + h) * S * HD;

  // Q as B-frag: col=q=ln, ch = half*16 + 8*hi + j
  bf16x8 qf0 = *(const bf16x8*)&Qh[(size_t)(q0 + ln) * HD + hi * 8];
  bf16x8 qf1 = *(const bf16x8*)&Qh[(size_t)(q0 + ln) * HD + 16 + hi * 8];

  const u16x8 ou = {0x3F80, 0x3F80, 0x3F80, 0x3F80, 0x3F80, 0x3F80, 0x3F80, 0x3F80};
  const bf16x8 ones = __builtin_bit_cast(bf16x8, ou);
  const f32x16 z = {};
  f32x16 acc = {};   // out^T tile: row=d, col=q
  f32x16 accl = {};  // softmax denom (all rows identical)

  const int kt0 = kp * (S / KSPLIT);
  // fragment-panel bases; every frag load = base + frag_offset + loff
  const int loff = ((lane & 31) * 2 + (lane >> 5)) * 8;
  const ushort* Kp = Kn + (size_t)(b * NH + h) * S * HD + (size_t)kt0 * 32 + loff;
  const ushort* Vp = Vt + (size_t)(b * NH + h) * HD * S + (size_t)kt0 * 32 + loff;

  bf16x8 kf0 = *(const bf16x8*)&Kp[0];
  bf16x8 kf1 = *(const bf16x8*)&Kp[512];
  bf16x8 kf2 = *(const bf16x8*)&Kp[1024];
  bf16x8 kf3 = *(const bf16x8*)&Kp[1536];
  bf16x8 vf0 = *(const bf16x8*)&Vp[0];
  bf16x8 vf1 = *(const bf16x8*)&Vp[512];
  bf16x8 vf2 = *(const bf16x8*)&Vp[1024];
  bf16x8 vf3 = *(const bf16x8*)&Vp[1536];

  #pragma unroll 1
  for (int it = 0; it < S / KSPLIT / 64; ++it) {
    Kp += 2048;
    Vp += 2048;

    // keys +0..31
    f32x16 s = __builtin_amdgcn_mfma_f32_32x32x16_bf16(kf0, qf0, z, 0, 0, 0);
    s = __builtin_amdgcn_mfma_f32_32x32x16_bf16(kf1, qf1, s, 0, 0, 0);
    kf0 = *(const bf16x8*)&Kp[0];       // prefetch next tile (overread stays in workspace)
    kf1 = *(const bf16x8*)&Kp[512];
    bf16x8 pf0, pf1;
    s_to_pf(s, pf0, pf1);
    acc = __builtin_amdgcn_mfma_f32_32x32x16_bf16(vf0, pf0, acc, 0, 0, 0);
    accl = __builtin_amdgcn_mfma_f32_32x32x16_bf16(ones, pf0, accl, 0, 0, 0);
    acc = __builtin_amdgcn_mfma_f32_32x32x16_bf16(vf1, pf1, acc, 0, 0, 0);
    accl = __builtin_amdgcn_mfma_f32_32x32x16_bf16(ones, pf1, accl, 0, 0, 0);

    // keys +32..63
    f32x16 t = __builtin_amdgcn_mfma_f32_32x32x16_bf16(kf2, qf0, z, 0, 0, 0);
    t = __builtin_amdgcn_mfma_f32_32x32x16_bf16(kf3, qf1, t, 0, 0, 0);
    kf2 = *(const bf16x8*)&Kp[1024];
    kf3 = *(const bf16x8*)&Kp[1536];
    bf16x8 pf2, pf3;
    s_to_pf(t, pf2, pf3);
    acc = __builtin_amdgcn_mfma_f32_32x32x16_bf16(vf2, pf2, acc, 0, 0, 0);
    accl = __builtin_amdgcn_mfma_f32_32x32x16_bf16(ones, pf2, accl, 0, 0, 0);
    acc = __builtin_amdgcn_mfma_f32_32x32x16_bf16(vf3, pf3, acc, 0, 0, 0);
    accl = __builtin_amdgcn_mfma_f32_32x32x16_bf16(ones, pf3, accl, 0, 0, 0);

    vf0 = *(const bf16x8*)&Vp[0];       // prefetch next tile's V (consumed mid-next-iter)
    vf1 = *(const bf16x8*)&Vp[512];
    vf2 = *(const bf16x8*)&Vp[1024];
    vf3 = *(const bf16x8*)&Vp[1536];
  }

  // acc[r]: d = (r&3) + 8*(r>>2) + 4*hi, q = ln
  float* ap = accP + ((size_t)((kp * 2 + b) * NH + h)) * S * HD;
  const size_t qrow = (size_t)(q0 + ln) * HD;
  #pragma unroll
  for (int g = 0; g < 4; g++) {
    float4 u;
    u.x = acc[4 * g + 0];
    u.y = acc[4 * g + 1];
    u.z = acc[4 * g + 2];
    u.w = acc[4 * g + 3];
    *(float4*)&ap[qrow + g * 8 + hi * 4] = u;
  }
  if (hi == 0)
    lP[((size_t)((kp * 2 + b) * NH + h)) * S + q0 + ln] = accl[0];
}

// ---------------- combine K-split partials -> Yt [b][s][256] bf16 ------------
__global__ __launch_bounds__(256) void combine_kernel(const float* __restrict__ accP,
                                                      const float* __restrict__ lP,
                                                      ushort* __restrict__ Yt) {
  const int tid = blockIdx.x * 256 + threadIdx.x;
  const int dg = tid & 7;
  const int q = (tid >> 3) & (S - 1);
  const int h = (tid >> 15) & 7;
  const int b = tid >> 18;
  const size_t i0 = ((size_t)(b * NH + h)) * S + q;
  const size_t part = (size_t)2 * NH * S;
  float sx = 0.f, sy = 0.f, sz = 0.f, sw = 0.f, L = 0.f;
  #pragma unroll
  for (int p = 0; p < KSPLIT; p++) {
    const float4 a = *(const float4*)&accP[(size_t)p * part * HD + i0 * HD + dg * 4];
    sx += a.x; sy += a.y; sz += a.z; sw += a.w;
    L += lP[(size_t)p * part + i0];
  }
  const float rl = 1.0f / L;
  ushort4 o;
  o.x = f2bf(sx * rl);
  o.y = f2bf(sy * rl);
  o.z = f2bf(sz * rl);
  o.w = f2bf(sw * rl);
  *(ushort4*)&Yt[((size_t)b * S + q) * CIN + h * HD + dg * 4] = o;
}

// ---------------- conv2: OUT[b][m][s] fp32 = Wo . Yt, fused mp_add -----------
__global__ __launch_bounds__(256) void conv2_kernel(const ushort* __restrict__ W,
                                                    const ushort* __restrict__ Bm,
                                                    const float* __restrict__ RES,
                                                    float* __restrict__ OUT) {
  const int b = blockIdx.z;
  const int wid = threadIdx.x >> 6, lane = threadIdx.x & 63;
  const int col = lane & 15, quad = lane >> 4;
  const int m0 = blockIdx.y * 64 + (wid >> 1) * 32;
  const int n0 = blockIdx.x * 128 + (wid & 1) * 64;
  const ushort* Bb = Bm + (size_t)b * S * CIN;
  f32x4 acc[2][4] = {};
  #pragma unroll
  for (int k0 = 0; k0 < CIN; k0 += 32) {
    bf16x8 af[2], bf[4];
    #pragma unroll
    for (int mi = 0; mi < 2; mi++)
      af[mi] = *(const bf16x8*)&W[(size_t)(m0 + mi * 16 + col) * CIN + k0 + quad * 8];
    #pragma unroll
    for (int ni = 0; ni < 4; ni++)
      bf[ni] = *(const bf16x8*)&Bb[(size_t)(n0 + ni * 16 + col) * CIN + k0 + quad * 8];
    #pragma unroll
    for (int mi = 0; mi < 2; mi++)
      #pragma unroll
      for (int ni = 0; ni < 4; ni++)
        acc[mi][ni] = __builtin_amdgcn_mfma_f32_16x16x32_bf16(af[mi], bf[ni], acc[mi][ni], 0, 0, 0);
  }
  const float tc = 0.3f, om = 0.7f, inv = 1.3130643285972254f;
  #pragma unroll
  for (int mi = 0; mi < 2; mi++)
    #pragma unroll
    for (int ni = 0; ni < 4; ni++)
      #pragma unroll
      for (int r = 0; r < 4; r++) {
        const size_t idx = ((size_t)(b * CIN + m0 + mi * 16 + quad * 4 + r)) * S + n0 + ni * 16 + col;
        OUT[idx] = (om * RES[idx] + tc * acc[mi][ni][r]) * inv;
      }
}

// ---------------- launch ----------------
extern "C" void kernel_launch(void* const* d_in, const int* in_sizes, int n_in,
                              void* d_out, int out_size, void* d_ws, size_t ws_size,
                              hipStream_t stream) {
  const float* x = (const float*)d_in[0];
  const float* w_qkv = (const float*)d_in[1];
  const float* w_out = (const float*)d_in[2];
  float* out = (float*)d_out;

  ushort* p = (ushort*)d_ws;
  ushort* wqb = p; p += (size_t)C3 * CIN;
  ushort* wob = p; p += (size_t)CIN * CIN;
  ushort* Qn = p; p += (size_t)2 * NH * S * HD;
  ushort* Kn = p; p += (size_t)2 * NH * S * HD;
  ushort* Vt = p; p += (size_t)2 * NH * S * HD;
  ushort* Yt = p; p += (size_t)2 * S * CIN;
  // Region R: Xt (4.2 MB bf16) dies after conv1_fused; accP fp32
  // (KSPLIT*2*8*4096*32 floats = 33.5 MB) aliases the same region.
  ushort* R = p; p += (size_t)KSPLIT * 2 * NH * S * HD * 2;  // 33.5 MB
  ushort* Xt = R;
  float* accP = (float*)R;
  float* lP = (float*)p;  // KSPLIT*2*8*4096 floats = 1 MB

  wnorm_kernel<<<(C3 + CIN) / 4, 256, 0, stream>>>(w_qkv, w_out, wqb, wob);
  xt_kernel<<<dim3(S / 64, CIN / 64, 2), 256, 0, stream>>>(x, Xt);
  conv1_fused_kernel<<<dim3(S / 128, C3 / 64, 2), 256, 0, stream>>>(wqb, Xt, Qn, Kn, Vt);
  attn_kernel<<<(S / 128) * NH * KSPLIT * 2, 256, 0, stream>>>(Qn, Kn, Vt, accP, lP);
  combine_kernel<<<2048, 256, 0, stream>>>(accP, lP, Yt);
  conv2_kernel<<<dim3(S / 128, CIN / 64, 2), 256, 0, stream>>>(wob, Yt, x, out);
}

// Round 5
// 155.979 us; speedup vs baseline: 4.4509x; 4.4509x over previous
//
#include <hip/hip_runtime.h>
#include <hip/hip_bf16.h>
#include <math.h>

#define S 4096
#define CIN 256
#define C3 768
#define NH 8
#define HD 32
#define KSPLIT 4

static constexpr float EPS = 1e-4f;

typedef __attribute__((ext_vector_type(8))) __bf16 bf16x8;
typedef __attribute__((ext_vector_type(4))) float f32x4;
typedef __attribute__((ext_vector_type(16))) float f32x16;
typedef __attribute__((ext_vector_type(4))) unsigned u32x4;

static inline __device__ ushort f2bf(float f) {  // RN-even
  unsigned u = __float_as_uint(f);
  return (ushort)((u + 0x7fffu + ((u >> 16) & 1u)) >> 16);
}

// v_cvt_pk_bf16_f32: dst.lo16 = bf16(lo), dst.hi16 = bf16(hi); RNE (no builtin)
static inline __device__ unsigned cvt_pk_bf16(float lo, float hi) {
  unsigned r;
  asm("v_cvt_pk_bf16_f32 %0, %1, %2" : "=v"(r) : "v"(lo), "v"(hi));
  return r;
}
// v_permlane32_swap_b32: a.hi32lanes <-> b.lo32lanes.
static inline __device__ void plane32_swap(unsigned& a, unsigned& b) {
  asm("v_permlane32_swap_b32 %0, %1" : "+v"(a), "+v"(b));
}

#define EXP2 __builtin_amdgcn_exp2f

// Convert one 32x32 QK score tile (D-layout: col=q=lane&31, row=k=(r&3)+8*(r>>2)+4*hi)
// to two PV operand fragments (col/row=q, k = frag*8 elements at 8*hi+j) fully
// in registers: 8 cvt_pk + 4 permlane32_swap. plo covers k 0..15, phi 16..31.
// Accumulates the lane's 16 exp values into lacc (softmax denominator partial;
// full denom for q=ln is lacc + shfl_xor(lacc,32)). Replaces the ones-MFMA
// (frees 16 AGPRs/tile, needed for the dual-q accumulators).
static inline __device__ void s_to_pf(const f32x16 s, bf16x8& plo, bf16x8& phi,
                                      float& lacc) {
  float e0 = EXP2(s[0]), e1 = EXP2(s[1]), e2 = EXP2(s[2]), e3 = EXP2(s[3]);
  float e4 = EXP2(s[4]), e5 = EXP2(s[5]), e6 = EXP2(s[6]), e7 = EXP2(s[7]);
  float e8 = EXP2(s[8]), e9 = EXP2(s[9]), e10 = EXP2(s[10]), e11 = EXP2(s[11]);
  float e12 = EXP2(s[12]), e13 = EXP2(s[13]), e14 = EXP2(s[14]), e15 = EXP2(s[15]);
  lacc += (((e0 + e1) + (e2 + e3)) + ((e4 + e5) + (e6 + e7))) +
          (((e8 + e9) + (e10 + e11)) + ((e12 + e13) + (e14 + e15)));
  unsigned c0 = cvt_pk_bf16(e0, e1);    // hi0:k(0,1)   hi1:k(4,5)
  unsigned c1 = cvt_pk_bf16(e2, e3);    // hi0:k(2,3)   hi1:k(6,7)
  unsigned c2 = cvt_pk_bf16(e4, e5);    // hi0:k(8,9)   hi1:k(12,13)
  unsigned c3 = cvt_pk_bf16(e6, e7);    // hi0:k(10,11) hi1:k(14,15)
  plane32_swap(c0, c2);
  plane32_swap(c1, c3);
  u32x4 lo4 = {c0, c1, c2, c3};
  plo = __builtin_bit_cast(bf16x8, lo4);
  unsigned c4 = cvt_pk_bf16(e8, e9);
  unsigned c5 = cvt_pk_bf16(e10, e11);
  unsigned c6 = cvt_pk_bf16(e12, e13);
  unsigned c7 = cvt_pk_bf16(e14, e15);
  plane32_swap(c4, c6);
  plane32_swap(c5, c7);
  u32x4 hi4 = {c4, c5, c6, c7};
  phi = __builtin_bit_cast(bf16x8, hi4);
}

// ---------------- weight norm (both weights, one launch) ---------------------
__global__ __launch_bounds__(256) void wnorm_kernel(const float* __restrict__ w_qkv,
                                                    const float* __restrict__ w_out,
                                                    ushort* __restrict__ wqb,
                                                    ushort* __restrict__ wob) {
  const int row = blockIdx.x * 4 + (threadIdx.x >> 6);
  const int lane = threadIdx.x & 63;
  const bool is_q = row < C3;
  const float* wr = (is_q ? w_qkv + (size_t)row * CIN : w_out + (size_t)(row - C3) * CIN);
  float v0 = wr[lane], v1 = wr[lane + 64], v2 = wr[lane + 128], v3 = wr[lane + 192];
  float ss = v0 * v0 + v1 * v1 + v2 * v2 + v3 * v3;
  #pragma unroll
  for (int off = 32; off > 0; off >>= 1) ss += __shfl_down(ss, off, 64);
  ss = __shfl(ss, 0, 64);
  const float scale = 1.0f / (sqrtf(ss) + 16.0f * EPS);
  ushort* whr = (is_q ? wqb + (size_t)row * CIN : wob + (size_t)(row - C3) * CIN);
  whr[lane] = f2bf(v0 * scale);
  whr[lane + 64] = f2bf(v1 * scale);
  whr[lane + 128] = f2bf(v2 * scale);
  whr[lane + 192] = f2bf(v3 * scale);
}

// ---------------- X [b][c][s] fp32 -> Xt [b][s][c] bf16 ----------------------
__global__ __launch_bounds__(256) void xt_kernel(const float* __restrict__ X,
                                                 ushort* __restrict__ Xt) {
  const int b = blockIdx.z;
  const int s0 = blockIdx.x * 64, c0 = blockIdx.y * 64;
  __shared__ ushort T[64][72];
  const int tc = threadIdx.x >> 4;
  const int ts = threadIdx.x & 15;
  #pragma unroll
  for (int i = 0; i < 4; i++) {
    const float4 v = *(const float4*)&X[((size_t)(b * CIN + c0 + tc + 16 * i)) * S + s0 + ts * 4];
    ushort4 u;
    u.x = f2bf(v.x); u.y = f2bf(v.y); u.z = f2bf(v.z); u.w = f2bf(v.w);
    *(ushort4*)&T[tc + 16 * i][ts * 4] = u;
  }
  __syncthreads();
  #pragma unroll
  for (int i = 0; i < 4; i++) {
    const int sr = tc + 16 * i;
    ushort4 u;
    u.x = T[ts * 4 + 0][sr];
    u.y = T[ts * 4 + 1][sr];
    u.z = T[ts * 4 + 2][sr];
    u.w = T[ts * 4 + 3][sr];
    *(ushort4*)&Xt[((size_t)b * S + s0 + sr) * CIN + c0 + ts * 4] = u;
  }
}

// ---------------- conv1 fused with pixel-norm + layout fan-out ---------------
// Q written as [bh][q][HD] rows (loaded once per attn wave). K and V written in
// MFMA-FRAGMENT-ORDERED PANELS so every attn fragment load is base + lane*16B
// (dense 1KB/instruction, 8 cache lines instead of 32-64):
//   Kpan: [bh][key>>5][half][key&31][hi][8]  (half = ch/16, hi = (ch&15)>>3)
//   Vpan: [bh][key>>6][kc][d][hi][8]         (kc = (key&63)>>4, hi = (key&15)>>3)
__global__ __launch_bounds__(256) void conv1_fused_kernel(const ushort* __restrict__ W,
                                                          const ushort* __restrict__ Bm,
                                                          ushort* __restrict__ Qn,
                                                          ushort* __restrict__ Kn,
                                                          ushort* __restrict__ Vt) {
  const int b = blockIdx.z;
  const int wid = threadIdx.x >> 6, lane = threadIdx.x & 63;
  const int col = lane & 15, quad = lane >> 4;
  const int m0 = blockIdx.y * 64 + (wid >> 1) * 32;  // 32-aligned: one head group
  const int n0 = blockIdx.x * 128 + (wid & 1) * 64;
  const ushort* Bb = Bm + (size_t)b * S * CIN;
  f32x4 acc[2][4] = {};
  #pragma unroll
  for (int k0 = 0; k0 < CIN; k0 += 32) {
    bf16x8 af[2], bf[4];
    #pragma unroll
    for (int mi = 0; mi < 2; mi++)
      af[mi] = *(const bf16x8*)&W[(size_t)(m0 + mi * 16 + col) * CIN + k0 + quad * 8];
    #pragma unroll
    for (int ni = 0; ni < 4; ni++)
      bf[ni] = *(const bf16x8*)&Bb[(size_t)(n0 + ni * 16 + col) * CIN + k0 + quad * 8];
    #pragma unroll
    for (int mi = 0; mi < 2; mi++)
      #pragma unroll
      for (int ni = 0; ni < 4; ni++)
        acc[mi][ni] = __builtin_amdgcn_mfma_f32_16x16x32_bf16(af[mi], bf[ni], acc[mi][ni], 0, 0, 0);
  }

  const int g = m0 >> 5;   // 0..23: group; 0-7 Q, 8-15 K, 16-23 V
  const int h = g & 7;
  float rn[4];
  #pragma unroll
  for (int ni = 0; ni < 4; ni++) {
    float ss = 0.f;
    #pragma unroll
    for (int mi = 0; mi < 2; mi++)
      #pragma unroll
      for (int r = 0; r < 4; r++) ss += acc[mi][ni][r] * acc[mi][ni][r];
    ss += __shfl_xor(ss, 16, 64);
    ss += __shfl_xor(ss, 32, 64);
    rn[ni] = rsqrtf(ss * (1.0f / HD) + EPS);
    if (g < 8) rn[ni] *= 0.2550348190698169f;  // log2(e)/sqrt(32) folded into Q
  }

  if (g < 8) {  // Q: row layout [q][HD]
    ushort* dst = Qn + (size_t)(b * NH + h) * S * HD;
    #pragma unroll
    for (int mi = 0; mi < 2; mi++)
      #pragma unroll
      for (int ni = 0; ni < 4; ni++) {
        ushort4 u;
        u.x = f2bf(acc[mi][ni][0] * rn[ni]);
        u.y = f2bf(acc[mi][ni][1] * rn[ni]);
        u.z = f2bf(acc[mi][ni][2] * rn[ni]);
        u.w = f2bf(acc[mi][ni][3] * rn[ni]);
        *(ushort4*)&dst[(size_t)(n0 + ni * 16 + col) * HD + mi * 16 + quad * 4] = u;
      }
  } else if (g < 16) {  // K: fragment panels
    // key = n0 + ni*16 + col; ch = mi*16 + quad*4 + r
    ushort* dst = Kn + (size_t)(b * NH + h) * S * HD + (size_t)(n0 >> 5) * 1024;
    #pragma unroll
    for (int mi = 0; mi < 2; mi++)
      #pragma unroll
      for (int ni = 0; ni < 4; ni++) {
        ushort4 u;
        u.x = f2bf(acc[mi][ni][0] * rn[ni]);
        u.y = f2bf(acc[mi][ni][1] * rn[ni]);
        u.z = f2bf(acc[mi][ni][2] * rn[ni]);
        u.w = f2bf(acc[mi][ni][3] * rn[ni]);
        *(ushort4*)&dst[(ni >> 1) * 1024 + mi * 512 + ((ni & 1) * 16 + col) * 16 +
                        (quad >> 1) * 8 + (quad & 1) * 4] = u;
      }
  } else {  // V: fragment panels (d = mi*16+quad*4+r, key = n0+ni*16+col)
    ushort* dst = Vt + (size_t)(b * NH + h) * HD * S + (size_t)(n0 >> 6) * 2048;
    #pragma unroll
    for (int mi = 0; mi < 2; mi++)
      #pragma unroll
      for (int ni = 0; ni < 4; ni++)
        #pragma unroll
        for (int r = 0; r < 4; r++)
          dst[ni * 512 + (mi * 16 + quad * 4 + r) * 16 + col] =
              f2bf(acc[mi][ni][r] * rn[ni]);
  }
}

// ---------------- MFMA attention: dual 32x32 q-tiles per wave ----------------
// S^T = K.Q^T via mfma_32x32x16 (Q pre-scaled -> exp2 direct). P rebuilt into
// the PV operand fragment in registers (T12). K/V read from fragment-ordered
// panels (dense base+lane*16B loads), prefetched one 32-key tile ahead.
// Each wave owns TWO q-tiles sharing the same K/V frags: while tile A is in
// its softmax VALU chain, tile B's QK/PV MFMAs are independent issue material
// (2x per-wave ILP to fill the QK->exp2->cvt->PV dependency stalls), and K/V
// loads are amortized 2x. Denominator via VALU adds in s_to_pf (frees the
// accl AGPRs; R2 verified numerics). Regs ~112 of the 128 cap at
// __launch_bounds__(256,4) -- DO NOT raise waves/EU: VGPR+AGPR share one file
// (R2/R4 spilled at (256,8)). KSPLIT=4 keeps grid at 1024 = 4 blocks/CU.
// Bijective XCD swizzle: each XCD owns 8 complete (b,kp,h) groups (K/V 1MB,
// L2-resident). Zero LDS.
__global__ __launch_bounds__(256, 4) void attn_kernel(const ushort* __restrict__ Qn,
                                                      const ushort* __restrict__ Kn,
                                                      const ushort* __restrict__ Vt,
                                                      float* __restrict__ accP,
                                                      float* __restrict__ lP) {
  const int NWG = (S / 256) * NH * KSPLIT * 2;  // 1024
  const int bid = blockIdx.x;
  const int id = (bid & 7) * (NWG / 8) + (bid >> 3);
  const int qt = id & 15;       // 16 q-tiles of 256 rows
  const int grp = id >> 4;      // ((b*KSPLIT + kp) << 3) | h
  const int h = grp & 7;
  const int kp = (grp >> 3) & (KSPLIT - 1);
  const int b = (grp >> 3) / KSPLIT;
  const int wid = threadIdx.x >> 6, lane = threadIdx.x & 63;
  const int ln = lane & 31, hi = lane >> 5;
  const int qA = qt * 256 + wid * 64;   // tile A rows qA..qA+31
  const int qB = qA + 32;               // tile B rows qB..qB+31

  const ushort* Qh = Qn + (size_t)(b * NH + h) * S * HD;

  // Q as B-frag: col=q=ln, ch = half*16 + 8*hi + j
  bf16x8 qfA0 = *(const bf16x8*)&Qh[(size_t)(qA + ln) * HD + hi * 8];
  bf16x8 qfA1 = *(const bf16x8*)&Qh[(size_t)(qA + ln) * HD + 16 + hi * 8];
  bf16x8 qfB0 = *(const bf16x8*)&Qh[(size_t)(qB + ln) * HD + hi * 8];
  bf16x8 qfB1 = *(const bf16x8*)&Qh[(size_t)(qB + ln) * HD + 16 + hi * 8];

  const f32x16 z = {};
  f32x16 accA = {}, accB = {};  // out^T tiles: row=d, col=q
  float laccA = 0.f, laccB = 0.f;

  const int kt0 = kp * (S / KSPLIT);
  // fragment-panel bases; every frag load = base + frag_offset + loff
  const int loff = (ln * 2 + hi) * 8;
  const ushort* Kp = Kn + (size_t)(b * NH + h) * S * HD + (size_t)kt0 * 32 + loff;
  const ushort* Vp = Vt + (size_t)(b * NH + h) * HD * S + (size_t)kt0 * 32 + loff;

  bf16x8 kf0 = *(const bf16x8*)&Kp[0];
  bf16x8 kf1 = *(const bf16x8*)&Kp[512];
  bf16x8 vf0 = *(const bf16x8*)&Vp[0];
  bf16x8 vf1 = *(const bf16x8*)&Vp[512];

  #pragma unroll 1
  for (int it = 0; it < S / KSPLIT / 32; ++it) {   // 32-key steps
    f32x16 sA = __builtin_amdgcn_mfma_f32_32x32x16_bf16(kf0, qfA0, z, 0, 0, 0);
    sA = __builtin_amdgcn_mfma_f32_32x32x16_bf16(kf1, qfA1, sA, 0, 0, 0);
    f32x16 sB = __builtin_amdgcn_mfma_f32_32x32x16_bf16(kf0, qfB0, z, 0, 0, 0);
    sB = __builtin_amdgcn_mfma_f32_32x32x16_bf16(kf1, qfB1, sB, 0, 0, 0);
    Kp += 1024;
    kf0 = *(const bf16x8*)&Kp[0];      // prefetch next tile's K (overread stays in ws)
    kf1 = *(const bf16x8*)&Kp[512];

    bf16x8 pfA0, pfA1;
    s_to_pf(sA, pfA0, pfA1, laccA);
    accA = __builtin_amdgcn_mfma_f32_32x32x16_bf16(vf0, pfA0, accA, 0, 0, 0);
    accA = __builtin_amdgcn_mfma_f32_32x32x16_bf16(vf1, pfA1, accA, 0, 0, 0);

    bf16x8 pfB0, pfB1;
    s_to_pf(sB, pfB0, pfB1, laccB);
    accB = __builtin_amdgcn_mfma_f32_32x32x16_bf16(vf0, pfB0, accB, 0, 0, 0);
    accB = __builtin_amdgcn_mfma_f32_32x32x16_bf16(vf1, pfB1, accB, 0, 0, 0);

    Vp += 1024;
    vf0 = *(const bf16x8*)&Vp[0];      // prefetch next tile's V
    vf1 = *(const bf16x8*)&Vp[512];
  }

  // acc[r]: d = (r&3) + 8*(r>>2) + 4*hi, q = ln
  float* ap = accP + ((size_t)((kp * 2 + b) * NH + h)) * S * HD;
  const size_t rowA = (size_t)(qA + ln) * HD;
  const size_t rowB = (size_t)(qB + ln) * HD;
  #pragma unroll
  for (int g = 0; g < 4; g++) {
    float4 u;
    u.x = accA[4 * g + 0];
    u.y = accA[4 * g + 1];
    u.z = accA[4 * g + 2];
    u.w = accA[4 * g + 3];
    *(float4*)&ap[rowA + g * 8 + hi * 4] = u;
    float4 v;
    v.x = accB[4 * g + 0];
    v.y = accB[4 * g + 1];
    v.z = accB[4 * g + 2];
    v.w = accB[4 * g + 3];
    *(float4*)&ap[rowB + g * 8 + hi * 4] = v;
  }
  const float lsA = laccA + __shfl_xor(laccA, 32, 64);
  const float lsB = laccB + __shfl_xor(laccB, 32, 64);
  if (hi == 0) {
    float* lp = lP + ((size_t)((kp * 2 + b) * NH + h)) * S;
    lp[qA + ln] = lsA;
    lp[qB + ln] = lsB;
  }
}

// ---------------- combine K-split partials -> Yt [b][s][256] bf16 ------------
__global__ __launch_bounds__(256) void combine_kernel(const float* __restrict__ accP,
                                                      const float* __restrict__ lP,
                                                      ushort* __restrict__ Yt) {
  const int tid = blockIdx.x * 256 + threadIdx.x;
  const int dg = tid & 7;
  const int q = (tid >> 3) & (S - 1);
  const int h = (tid >> 15) & 7;
  const int b = tid >> 18;
  const size_t i0 = ((size_t)(b * NH + h)) * S + q;
  const size_t part = (size_t)2 * NH * S;
  float sx = 0.f, sy = 0.f, sz = 0.f, sw = 0.f, L = 0.f;
  #pragma unroll
  for (int p = 0; p < KSPLIT; p++) {
    const float4 a = *(const float4*)&accP[(size_t)p * part * HD + i0 * HD + dg * 4];
    sx += a.x; sy += a.y; sz += a.z; sw += a.w;
    L += lP[(size_t)p * part + i0];
  }
  const float rl = 1.0f / L;
  ushort4 o;
  o.x = f2bf(sx * rl);
  o.y = f2bf(sy * rl);
  o.z = f2bf(sz * rl);
  o.w = f2bf(sw * rl);
  *(ushort4*)&Yt[((size_t)b * S + q) * CIN + h * HD + dg * 4] = o;
}

// ---------------- conv2: OUT[b][m][s] fp32 = Wo . Yt, fused mp_add -----------
__global__ __launch_bounds__(256) void conv2_kernel(const ushort* __restrict__ W,
                                                    const ushort* __restrict__ Bm,
                                                    const float* __restrict__ RES,
                                                    float* __restrict__ OUT) {
  const int b = blockIdx.z;
  const int wid = threadIdx.x >> 6, lane = threadIdx.x & 63;
  const int col = lane & 15, quad = lane >> 4;
  const int m0 = blockIdx.y * 64 + (wid >> 1) * 32;
  const int n0 = blockIdx.x * 128 + (wid & 1) * 64;
  const ushort* Bb = Bm + (size_t)b * S * CIN;
  f32x4 acc[2][4] = {};
  #pragma unroll
  for (int k0 = 0; k0 < CIN; k0 += 32) {
    bf16x8 af[2], bf[4];
    #pragma unroll
    for (int mi = 0; mi < 2; mi++)
      af[mi] = *(const bf16x8*)&W[(size_t)(m0 + mi * 16 + col) * CIN + k0 + quad * 8];
    #pragma unroll
    for (int ni = 0; ni < 4; ni++)
      bf[ni] = *(const bf16x8*)&Bb[(size_t)(n0 + ni * 16 + col) * CIN + k0 + quad * 8];
    #pragma unroll
    for (int mi = 0; mi < 2; mi++)
      #pragma unroll
      for (int ni = 0; ni < 4; ni++)
        acc[mi][ni] = __builtin_amdgcn_mfma_f32_16x16x32_bf16(af[mi], bf[ni], acc[mi][ni], 0, 0, 0);
  }
  const float tc = 0.3f, om = 0.7f, inv = 1.3130643285972254f;
  #pragma unroll
  for (int mi = 0; mi < 2; mi++)
    #pragma unroll
    for (int ni = 0; ni < 4; ni++)
      #pragma unroll
      for (int r = 0; r < 4; r++) {
        const size_t idx = ((size_t)(b * CIN + m0 + mi * 16 + quad * 4 + r)) * S + n0 + ni * 16 + col;
        OUT[idx] = (om * RES[idx] + tc * acc[mi][ni][r]) * inv;
      }
}

// ---------------- launch ----------------
extern "C" void kernel_launch(void* const* d_in, const int* in_sizes, int n_in,
                              void* d_out, int out_size, void* d_ws, size_t ws_size,
                              hipStream_t stream) {
  const float* x = (const float*)d_in[0];
  const float* w_qkv = (const float*)d_in[1];
  const float* w_out = (const float*)d_in[2];
  float* out = (float*)d_out;

  ushort* p = (ushort*)d_ws;
  ushort* wqb = p; p += (size_t)C3 * CIN;
  ushort* wob = p; p += (size_t)CIN * CIN;
  ushort* Qn = p; p += (size_t)2 * NH * S * HD;
  ushort* Kn = p; p += (size_t)2 * NH * S * HD;
  ushort* Vt = p; p += (size_t)2 * NH * S * HD;
  ushort* Yt = p; p += (size_t)2 * S * CIN;
  // Region R: Xt (4.2 MB bf16) dies after conv1_fused; accP fp32
  // (KSPLIT*2*8*4096*32 floats = 33.5 MB) aliases the same region.
  ushort* R = p; p += (size_t)KSPLIT * 2 * NH * S * HD * 2;  // 33.5 MB
  ushort* Xt = R;
  float* accP = (float*)R;
  float* lP = (float*)p;  // KSPLIT*2*8*4096 floats = 1 MB

  wnorm_kernel<<<(C3 + CIN) / 4, 256, 0, stream>>>(w_qkv, w_out, wqb, wob);
  xt_kernel<<<dim3(S / 64, CIN / 64, 2), 256, 0, stream>>>(x, Xt);
  conv1_fused_kernel<<<dim3(S / 128, C3 / 64, 2), 256, 0, stream>>>(wqb, Xt, Qn, Kn, Vt);
  attn_kernel<<<(S / 256) * NH * KSPLIT * 2, 256, 0, stream>>>(Qn, Kn, Vt, accP, lP);
  combine_kernel<<<2048, 256, 0, stream>>>(accP, lP, Yt);
  conv2_kernel<<<dim3(S / 128, CIN / 64, 2), 256, 0, stream>>>(wob, Yt, x, out);
}